// Round 9
// baseline (311.840 us; speedup 1.0000x reference)
//
#include <hip/hip_runtime.h>
#include <hip/hip_bf16.h>
#include <hip/hip_fp16.h>
#include <math.h>

// Problem constants
#define TOKENS   8192
#define DIM      4096
#define NEXP     256
#define TOPK     8
#define CAND     12

// GEMM tiling
#define MT4      128               // tokens per block (round 9: 64 -> 128)
#define BK3      64                // k per staged chunk
#define KG       (DIM / 32)        // 128 k-fragment-groups in W

typedef _Float16 f16x8 __attribute__((ext_vector_type(8)));
typedef float    f32x4 __attribute__((ext_vector_type(4)));

typedef const __attribute__((address_space(1))) unsigned int* gas_ptr;
typedef       __attribute__((address_space(3))) unsigned int* las_ptr;

// ---------------------------------------------------------------------------
// Kernel 0: W fp32 -> fp16 in MFMA-B-fragment-swizzled order.
// 1 KB tiles, tile = ng*KG + kg covers experts [ng*16,+16) x k [kg*32,+32);
// chunk c = q*16+r holds B[n=ng*16+r][k=kg*32+q*8..+8] = lane c's B-fragment.
// ---------------------------------------------------------------------------
__global__ __launch_bounds__(256)
void convert_w(const float* __restrict__ w, _Float16* __restrict__ whs) {
    const int g = blockIdx.x * 256 + threadIdx.x;   // chunk id, 131072 total
    const int tile = g >> 6, c = g & 63;
    const int q = c >> 4, r = c & 15;
    const int ng = tile / KG, kg = tile % KG;
    const int n = ng * 16 + r, k = kg * 32 + q * 8;
    const float4 a = *(const float4*)(w + (size_t)n * DIM + k);
    const float4 b = *(const float4*)(w + (size_t)n * DIM + k + 4);
    f16x8 h;
    h[0] = (_Float16)a.x; h[1] = (_Float16)a.y;
    h[2] = (_Float16)a.z; h[3] = (_Float16)a.w;
    h[4] = (_Float16)b.x; h[5] = (_Float16)b.y;
    h[6] = (_Float16)b.z; h[7] = (_Float16)b.w;
    *(f16x8*)(whs + (size_t)g * 8) = h;
}

// ---------------------------------------------------------------------------
// Kernel 1: partial logits via fp16 MFMA, K-split over blockIdx.y.
// Round 9: MT4 128, 512 threads (8 waves, 2M x 4N wave grid, 64x64 wave
// tile). Round-8 accounting: gemm ~75us vs ~22-30us x-HBM floor; MFMA only
// ~2us; whs (B) re-reads = 268 MB of burst cache traffic through the
// per-step barrier drain — the one term that scales 1/MT4. This halves it
// (134 MB, 32 KB/CU/step burst). 2-phase double-buffer kept: stage k+1's B
// + write k+1's A before computing k; one barrier per step. LDS 2x(16+32)
// = 96 KB -> 1 block/CU; grid (64,S) = 256 blocks = exactly co-resident.
// ---------------------------------------------------------------------------
__global__ __launch_bounds__(512, 1)
void gemm_v4(const float* __restrict__ x, const _Float16* __restrict__ whs,
             float* __restrict__ logits, int kspan) {
    __shared__ _Float16 As[2][16 * 512];    // 2 x 16 KB (16 tiles: 8 mgrp x 2 kk)
    __shared__ _Float16 Bs[2][32 * 512];    // 2 x 32 KB

    const int t = threadIdx.x, w = t >> 6, lane = t & 63;
    const int wm = w >> 2, wn = w & 3;      // wave grid: 2M x 4N
    const int m0 = blockIdx.x * MT4;
    const int kb = blockIdx.y * kspan;
    const int kend = kb + kspan;
    float* lp    = logits + (size_t)blockIdx.y * TOKENS * NEXP;

    // A staging: thread t -> row am (0..127), k-chunks ack, ack+1 (8 halves ea)
    const int am  = t >> 2;
    const int ack = (t & 3) * 2;
    const int amg = am >> 4, amr = am & 15;
    const int aoff0 = ((amg * 2 + (ack >> 2)) * 64 + (ack & 3) * 16 + amr) * 8;
    const int ack1  = ack + 1;
    const int aoff1 = ((amg * 2 + (ack1 >> 2)) * 64 + (ack1 & 3) * 16 + amr) * 8;

    f32x4 acc[4][4];
    #pragma unroll
    for (int i = 0; i < 4; ++i)
        #pragma unroll
        for (int j = 0; j < 4; ++j) acc[i][j] = (f32x4){0.f, 0.f, 0.f, 0.f};

    const float* xrow = x + (size_t)(m0 + am) * DIM + ack * 8;

    // ---- helpers as lambdas (compile-time inlined) ----
    auto stage_B = [&](int buf, int k0) {
        #pragma unroll
        for (int c = 0; c < 4; ++c) {       // 8 waves x 4 tiles = 32 tiles
            const int ti  = w * 4 + c;
            const int ng  = ti >> 1, kgl = ti & 1;
            const _Float16* gp = whs + ((size_t)(ng * KG + (k0 >> 5) + kgl)) * 512
                                     + lane * 8;
            __builtin_amdgcn_global_load_lds((gas_ptr)gp,
                                             (las_ptr)&Bs[buf][ti * 512],
                                             16, 0, 0);
        }
    };
    auto write_A = [&](int buf, const float4& r0, const float4& r1,
                       const float4& r2, const float4& r3) {
        f16x8 h0, h1;
        h0[0] = (_Float16)r0.x; h0[1] = (_Float16)r0.y;
        h0[2] = (_Float16)r0.z; h0[3] = (_Float16)r0.w;
        h0[4] = (_Float16)r1.x; h0[5] = (_Float16)r1.y;
        h0[6] = (_Float16)r1.z; h0[7] = (_Float16)r1.w;
        h1[0] = (_Float16)r2.x; h1[1] = (_Float16)r2.y;
        h1[2] = (_Float16)r2.z; h1[3] = (_Float16)r2.w;
        h1[4] = (_Float16)r3.x; h1[5] = (_Float16)r3.y;
        h1[6] = (_Float16)r3.z; h1[7] = (_Float16)r3.w;
        *(f16x8*)&As[buf][aoff0] = h0;
        *(f16x8*)&As[buf][aoff1] = h1;
    };

    // ---- prologue: stage step 0 into buf 0; prefetch step-1 x ----
    {
        float4 r0 = *(const float4*)(xrow + kb);
        float4 r1 = *(const float4*)(xrow + kb + 4);
        float4 r2 = *(const float4*)(xrow + kb + 8);
        float4 r3 = *(const float4*)(xrow + kb + 12);
        stage_B(0, kb);
        write_A(0, r0, r1, r2, r3);
    }
    float4 xn0, xn1, xn2, xn3;
    if (kb + BK3 < kend) {
        xn0 = *(const float4*)(xrow + kb + BK3);
        xn1 = *(const float4*)(xrow + kb + BK3 + 4);
        xn2 = *(const float4*)(xrow + kb + BK3 + 8);
        xn3 = *(const float4*)(xrow + kb + BK3 + 12);
    }
    __syncthreads();    // buf0 ready (drains vmcnt + lgkm)

    int cur = 0;
    for (int k0 = kb; k0 < kend; k0 += BK3) {
        const int nxt = cur ^ 1;
        const bool has_next = (k0 + BK3 < kend);

        // issue next step's B staging first (latency hides under compute)
        if (has_next) stage_B(nxt, k0 + BK3);

        // compute current step: wave (wm,wn) owns rows wm*64..+64, cols wn*64..+64
        #pragma unroll
        for (int kk = 0; kk < 2; ++kk) {
            f16x8 af[4], bf[4];
            #pragma unroll
            for (int mt = 0; mt < 4; ++mt)
                af[mt] = *(const f16x8*)&As[cur][(((wm * 4 + mt) * 2 + kk) * 64 + lane) * 8];
            #pragma unroll
            for (int nt = 0; nt < 4; ++nt)
                bf[nt] = *(const f16x8*)&Bs[cur][(((wn * 4 + nt) * 2 + kk) * 64 + lane) * 8];
            #pragma unroll
            for (int mt = 0; mt < 4; ++mt)
                #pragma unroll
                for (int nt = 0; nt < 4; ++nt)
                    acc[mt][nt] = __builtin_amdgcn_mfma_f32_16x16x32_f16(
                        af[mt], bf[nt], acc[mt][nt], 0, 0, 0);
        }

        // write next step's A (xn loaded one step ago)
        if (has_next) write_A(nxt, xn0, xn1, xn2, xn3);

        __syncthreads();    // nxt buffers ready for next iter

        // prefetch x for step k+2
        if (k0 + 2 * BK3 < kend) {
            xn0 = *(const float4*)(xrow + k0 + 2 * BK3);
            xn1 = *(const float4*)(xrow + k0 + 2 * BK3 + 4);
            xn2 = *(const float4*)(xrow + k0 + 2 * BK3 + 8);
            xn3 = *(const float4*)(xrow + k0 + 2 * BK3 + 12);
        }
        cur = nxt;
    }

    // epilogue: C/D layout col=lane&15, row=(lane>>4)*4+reg
    #pragma unroll
    for (int mt = 0; mt < 4; ++mt) {
        #pragma unroll
        for (int nt = 0; nt < 4; ++nt) {
            #pragma unroll
            for (int r = 0; r < 4; ++r) {
                const int m = m0 + (wm * 4 + mt) * 16 + (lane >> 4) * 4 + r;
                const int n = (wn * 4 + nt) * 16 + (lane & 15);
                lp[(size_t)m * NEXP + n] = acc[mt][nt][r];
            }
        }
    }
}

// ---------------------------------------------------------------------------
// Kernel 2: sum K-split planes, per-token top-CAND candidates. One wave/token.
// ---------------------------------------------------------------------------
__global__ __launch_bounds__(256)
void topk_cand(const float* __restrict__ logits, int* __restrict__ cand,
               int nsplit) {
    const int lane  = threadIdx.x & 63;
    const int token = blockIdx.x * 4 + (threadIdx.x >> 6);
    const float* lp = logits + (size_t)token * NEXP;

    float s[4];
    #pragma unroll
    for (int j = 0; j < 4; ++j) s[j] = 0.f;
    for (int p = 0; p < nsplit; ++p) {
        const float* pp = lp + (size_t)p * TOKENS * NEXP;
        #pragma unroll
        for (int j = 0; j < 4; ++j) s[j] += pp[j * 64 + lane];
    }

    int mye = 0;
    #pragma unroll
    for (int r = 0; r < CAND; ++r) {
        float bv = s[0];
        int   be = lane;
        #pragma unroll
        for (int j = 1; j < 4; ++j) {
            if (s[j] > bv) { bv = s[j]; be = j * 64 + lane; }
        }
        #pragma unroll
        for (int off = 32; off > 0; off >>= 1) {
            const float ov = __shfl_xor(bv, off, 64);
            const int   oe = __shfl_xor(be, off, 64);
            if (ov > bv || (ov == bv && oe < be)) { bv = ov; be = oe; }
        }
        if (lane == r) mye = be;
        if ((be & 63) == lane) s[be >> 6] = -1e30f;
    }

    if (lane < CAND) cand[token * CAND + lane] = mye;
}

// ---------------------------------------------------------------------------
// Kernel 3: fp64 rescore — round-5 structure + depth-4 W prefetch (proven
// 81-82us, ~19 TB/s cache service; depth-4 == depth-3 -> at its operating
// floor for this algorithm). FROZEN this round.
// ---------------------------------------------------------------------------
__global__ __launch_bounds__(256)
void rescore(const float* __restrict__ x, const float* __restrict__ w,
             const int* __restrict__ cand, float* __restrict__ out) {
    __shared__ float  xs[DIM];          // 16 KB: this token's x row
    __shared__ double stot[CAND];
    __shared__ int    sce[CAND];

    const int t = threadIdx.x, wave = t >> 6, lane = t & 63;
    const int token = blockIdx.x;

    // Stage x row -> LDS, NT (read-once stream).
    const float* xrow = x + (size_t)token * DIM;
    #pragma unroll
    for (int r = 0; r < 4; ++r) {
        const float* gp = xrow + r * 1024 + wave * 256 + lane * 4;
        __builtin_amdgcn_global_load_lds((gas_ptr)gp,
                                         (las_ptr)&xs[r * 1024 + wave * 256],
                                         16, 0, 2 /* NT */);
    }

    // This wave's 3 candidates (scalarized bases).
    int ce[3];
    const f32x4* wp[3];
    #pragma unroll
    for (int j = 0; j < 3; ++j) {
        ce[j] = __builtin_amdgcn_readfirstlane(cand[token * CAND + wave * 3 + j]);
        wp[j] = (const f32x4*)(w + (size_t)ce[j] * DIM);
    }

    double acc[3];
    #pragma unroll
    for (int j = 0; j < 3; ++j) acc[j] = 0.0;

    // Depth-4 buffer: loads for iter i issue at iter i-3 (9 outstanding).
    f32x4 wb[4][3];
    #pragma unroll
    for (int j = 0; j < 3; ++j) wb[0][j] = wp[j][lane];
    #pragma unroll
    for (int j = 0; j < 3; ++j) wb[1][j] = wp[j][64 + lane];
    #pragma unroll
    for (int j = 0; j < 3; ++j) wb[2][j] = wp[j][128 + lane];

    __syncthreads();   // xs ready (syncthreads drains vmcnt before barrier)

    #pragma unroll
    for (int i = 0; i < 16; ++i) {
        const int cur = i & 3, nxt = (i + 3) & 3;   // constants under unroll
        if (i < 13) {
            const int o = lane + (i + 3) * 64;
            #pragma unroll
            for (int j = 0; j < 3; ++j) wb[nxt][j] = wp[j][o];
        }
        const f32x4 xv = *(const f32x4*)&xs[(lane + i * 64) * 4];
        const double dx = (double)xv.x, dy = (double)xv.y;
        const double dz = (double)xv.z, dw = (double)xv.w;
        #pragma unroll
        for (int j = 0; j < 3; ++j) {
            const f32x4 wv = wb[cur][j];
            acc[j] = fma(dw, (double)wv.w,
                     fma(dz, (double)wv.z,
                     fma(dy, (double)wv.y,
                     fma(dx, (double)wv.x, acc[j]))));
        }
    }

    // Lane reduce within wave.
    #pragma unroll
    for (int off = 32; off > 0; off >>= 1) {
        #pragma unroll
        for (int j = 0; j < 3; ++j)
            acc[j] += __shfl_xor(acc[j], off, 64);
    }

    if (lane == 0) {
        #pragma unroll
        for (int j = 0; j < 3; ++j) {
            stot[wave * 3 + j] = acc[j];
            sce[wave * 3 + j]  = ce[j];
        }
    }
    __syncthreads();

    // Wave 0: rank the 12 candidates, sigmoid, normalize, write.
    if (wave == 0) {
        double tt[CAND];
        int    ee[CAND];
        #pragma unroll
        for (int c = 0; c < CAND; ++c) { tt[c] = stot[c]; ee[c] = sce[c]; }

        int rank[CAND];
        #pragma unroll
        for (int c = 0; c < CAND; ++c) {
            int r = 0;
            #pragma unroll
            for (int j = 0; j < CAND; ++j) {
                if (j == c) continue;
                if (tt[j] > tt[c] || (tt[j] == tt[c] && ee[j] < ee[c])) ++r;
            }
            rank[c] = r;
        }

        float sig[CAND];
        float sum = 0.f;
        #pragma unroll
        for (int c = 0; c < CAND; ++c) {
            sig[c] = 1.0f / (1.0f + expf(-(float)tt[c]));
            if (rank[c] < TOPK) sum += sig[c];
        }

        if (lane < TOPK) {
            float g = 0.f; int ei = 0;
            #pragma unroll
            for (int c = 0; c < CAND; ++c)
                if (rank[c] == lane) { g = sig[c]; ei = ee[c]; }
            out[(size_t)token * TOPK + lane] = g / sum;
            out[(size_t)TOKENS * TOPK + (size_t)token * TOPK + lane] = (float)ei;
        }
    }
}

extern "C" void kernel_launch(void* const* d_in, const int* in_sizes, int n_in,
                              void* d_out, int out_size, void* d_ws, size_t ws_size,
                              hipStream_t stream) {
    const float* x = (const float*)d_in[0];   // [8192, 4096]
    const float* w = (const float*)d_in[1];   // [256, 4096]
    float* out     = (float*)d_out;

    const size_t plane = (size_t)TOKENS * NEXP * sizeof(float);   // 8 MB
    const size_t fixed = (size_t)TOKENS * CAND * sizeof(int)
                       + (size_t)NEXP * DIM * sizeof(_Float16);
    int S = 4;
    if (ws_size < 4 * plane + fixed) S = (ws_size >= 2 * plane + fixed) ? 2 : 1;

    float*     logits = (float*)d_ws;
    int*       candp  = (int*)((char*)d_ws + (size_t)S * plane);
    _Float16*  whs    = (_Float16*)((char*)candp + (size_t)TOKENS * CAND * sizeof(int));

    convert_w<<<512, 256, 0, stream>>>(w, whs);
    dim3 ggrid(TOKENS / MT4, S);
    gemm_v4<<<ggrid, 512, 0, stream>>>(x, whs, logits, DIM / S);
    topk_cand<<<TOKENS / 4, 256, 0, stream>>>(logits, candp, S);
    rescore<<<TOKENS, 256, 0, stream>>>(x, w, candp, out);
}

// Round 10
// 306.868 us; speedup vs baseline: 1.0162x; 1.0162x over previous
//
#include <hip/hip_runtime.h>
#include <hip/hip_bf16.h>
#include <hip/hip_fp16.h>
#include <math.h>

// Problem constants
#define TOKENS   8192
#define DIM      4096
#define NEXP     256
#define TOPK     8
#define CAND     12

// GEMM tiling
#define MT4      128               // tokens per block
#define BK3      64                // k per staged chunk
#define KG       (DIM / 32)        // 128 k-fragment-groups in W

typedef _Float16 f16x8 __attribute__((ext_vector_type(8)));
typedef float    f32x4 __attribute__((ext_vector_type(4)));

typedef const __attribute__((address_space(1))) unsigned int* gas_ptr;
typedef       __attribute__((address_space(3))) unsigned int* las_ptr;

// ---------------------------------------------------------------------------
// Kernel 0: W fp32 -> fp16 in MFMA-B-fragment-swizzled order. (frozen)
// ---------------------------------------------------------------------------
__global__ __launch_bounds__(256)
void convert_w(const float* __restrict__ w, _Float16* __restrict__ whs) {
    const int g = blockIdx.x * 256 + threadIdx.x;   // chunk id, 131072 total
    const int tile = g >> 6, c = g & 63;
    const int q = c >> 4, r = c & 15;
    const int ng = tile / KG, kg = tile % KG;
    const int n = ng * 16 + r, k = kg * 32 + q * 8;
    const float4 a = *(const float4*)(w + (size_t)n * DIM + k);
    const float4 b = *(const float4*)(w + (size_t)n * DIM + k + 4);
    f16x8 h;
    h[0] = (_Float16)a.x; h[1] = (_Float16)a.y;
    h[2] = (_Float16)a.z; h[3] = (_Float16)a.w;
    h[4] = (_Float16)b.x; h[5] = (_Float16)b.y;
    h[6] = (_Float16)b.z; h[7] = (_Float16)b.w;
    *(f16x8*)(whs + (size_t)g * 8) = h;
}

// ---------------------------------------------------------------------------
// Kernel 1: partial logits via fp16 MFMA, K-split over blockIdx.y.
// Round 10: triple-buffered counted-vmcnt pipeline (T3+T4).
// Round-9 counters: MfmaUtil 7.9%, VALUBusy 5.2%, HBM 1.35 TB/s — every
// pipe idle; 3 structurally different gemms all ~5us/K-step. Diagnosis:
// __syncthreads drains vmcnt(0) every step -> <=48 KB/CU in flight, full
// drain, ~1.4 TB/s delivery. Fix (T4): raw s_barrier + counted
// s_waitcnt vmcnt(K) — staging for steps i+1 AND i+2 stays in flight
// across barriers; K never 0 in steady state.
// Schedule per iter i (compute buf i%3):
//   write_A(i+2)          [ds_write from regs; buf (i+2)%3==(i-1)%3, whose
//                          reads finished before end-of-iter-(i-1) barrier]
//   load x(i+3) -> regs   [after write_A so reg-dep auto-wait doesn't
//                          force iter-(i-1) B-loads early]
//   stage_B(i+2)          [4 global_load_lds/wave]
//   s_waitcnt vmcnt(K) lgkmcnt(0)  [K = issues(i-1)+issues(i): my buf-i
//                          staging confirmed; lgkm drains my ds_writes]
//   s_barrier             [-> ALL waves confirmed buf i]
//   compute(i)            [ds_read + 32 MFMA]
//   s_barrier             [all done reading buf i%3 -> restage-safe]
// K_i: issues(j) = 4*[j+2<steps] (B) + 4*[j+3<steps] (x). Steady 16;
// i=0:8, tail 12/4/0 — exact, so tail staging is always covered.
// LDS 3x(16+32) = 144 KB -> 1 block/CU; grid (64,S) co-resident.
// ---------------------------------------------------------------------------
__global__ __launch_bounds__(512, 1)
void gemm_v4(const float* __restrict__ x, const _Float16* __restrict__ whs,
             float* __restrict__ logits, int kspan) {
    __shared__ _Float16 As[3][16 * 512];    // 3 x 16 KB
    __shared__ _Float16 Bs[3][32 * 512];    // 3 x 32 KB  (total 144 KB)

    const int t = threadIdx.x, w = t >> 6, lane = t & 63;
    const int wm = w >> 2, wn = w & 3;      // wave grid: 2M x 4N
    const int m0 = blockIdx.x * MT4;
    const int kb = blockIdx.y * kspan;
    const int steps = kspan / BK3;          // >= 16 for S<=4
    float* lp = logits + (size_t)blockIdx.y * TOKENS * NEXP;

    // A staging: thread t -> row am (0..127), k-chunks ack, ack+1
    const int am  = t >> 2;
    const int ack = (t & 3) * 2;
    const int amg = am >> 4, amr = am & 15;
    const int aoff0 = ((amg * 2 + (ack >> 2)) * 64 + (ack & 3) * 16 + amr) * 8;
    const int ack1  = ack + 1;
    const int aoff1 = ((amg * 2 + (ack1 >> 2)) * 64 + (ack1 & 3) * 16 + amr) * 8;

    f32x4 acc[4][4];
    #pragma unroll
    for (int i = 0; i < 4; ++i)
        #pragma unroll
        for (int j = 0; j < 4; ++j) acc[i][j] = (f32x4){0.f, 0.f, 0.f, 0.f};

    const float* xrow = x + (size_t)(m0 + am) * DIM + ack * 8;

    auto stage_B = [&](int buf, int k0) {
        #pragma unroll
        for (int c = 0; c < 4; ++c) {       // 8 waves x 4 tiles = 32 tiles
            const int ti  = w * 4 + c;
            const int ng  = ti >> 1, kgl = ti & 1;
            const _Float16* gp = whs + ((size_t)(ng * KG + (k0 >> 5) + kgl)) * 512
                                     + lane * 8;
            __builtin_amdgcn_global_load_lds((gas_ptr)gp,
                                             (las_ptr)&Bs[buf][ti * 512],
                                             16, 0, 0);
        }
    };
    auto write_A = [&](int buf, const float4& r0, const float4& r1,
                       const float4& r2, const float4& r3) {
        f16x8 h0, h1;
        h0[0] = (_Float16)r0.x; h0[1] = (_Float16)r0.y;
        h0[2] = (_Float16)r0.z; h0[3] = (_Float16)r0.w;
        h0[4] = (_Float16)r1.x; h0[5] = (_Float16)r1.y;
        h0[6] = (_Float16)r1.z; h0[7] = (_Float16)r1.w;
        h1[0] = (_Float16)r2.x; h1[1] = (_Float16)r2.y;
        h1[2] = (_Float16)r2.z; h1[3] = (_Float16)r2.w;
        h1[4] = (_Float16)r3.x; h1[5] = (_Float16)r3.y;
        h1[6] = (_Float16)r3.z; h1[7] = (_Float16)r3.w;
        *(f16x8*)&As[buf][aoff0] = h0;
        *(f16x8*)&As[buf][aoff1] = h1;
    };
    auto compute = [&](int buf) {
        #pragma unroll
        for (int kk = 0; kk < 2; ++kk) {
            f16x8 af[4], bf[4];
            #pragma unroll
            for (int mt = 0; mt < 4; ++mt)
                af[mt] = *(const f16x8*)&As[buf][(((wm * 4 + mt) * 2 + kk) * 64 + lane) * 8];
            #pragma unroll
            for (int nt = 0; nt < 4; ++nt)
                bf[nt] = *(const f16x8*)&Bs[buf][(((wn * 4 + nt) * 2 + kk) * 64 + lane) * 8];
            #pragma unroll
            for (int mt = 0; mt < 4; ++mt)
                #pragma unroll
                for (int nt = 0; nt < 4; ++nt)
                    acc[mt][nt] = __builtin_amdgcn_mfma_f32_16x16x32_f16(
                        af[mt], bf[nt], acc[mt][nt], 0, 0, 0);
        }
    };
    auto wait_vm = [](int k) {      // counted wait; K in {0,4,8,12,>=16}
        switch (k) {
            case 0:  asm volatile("s_waitcnt vmcnt(0) lgkmcnt(0)"  ::: "memory"); break;
            case 4:  asm volatile("s_waitcnt vmcnt(4) lgkmcnt(0)"  ::: "memory"); break;
            case 8:  asm volatile("s_waitcnt vmcnt(8) lgkmcnt(0)"  ::: "memory"); break;
            case 12: asm volatile("s_waitcnt vmcnt(12) lgkmcnt(0)" ::: "memory"); break;
            default: asm volatile("s_waitcnt vmcnt(16) lgkmcnt(0)" ::: "memory"); break;
        }
    };

    // ---- prologue: stage steps 0,1; preload x(step2); full drain ----
    {
        const float* p0 = xrow + kb;
        const float* p1 = xrow + kb + BK3;
        float4 a0 = *(const float4*)(p0),     a1 = *(const float4*)(p0 + 4);
        float4 a2 = *(const float4*)(p0 + 8), a3 = *(const float4*)(p0 + 12);
        float4 b0 = *(const float4*)(p1),     b1 = *(const float4*)(p1 + 4);
        float4 b2 = *(const float4*)(p1 + 8), b3 = *(const float4*)(p1 + 12);
        stage_B(0, kb);
        stage_B(1, kb + BK3);
        write_A(0, a0, a1, a2, a3);
        write_A(1, b0, b1, b2, b3);
    }
    float4 xc0, xc1, xc2, xc3;                  // invariant: xc = x(step i+2)
    {
        const float* p2 = xrow + kb + 2 * BK3;
        xc0 = *(const float4*)(p2);      xc1 = *(const float4*)(p2 + 4);
        xc2 = *(const float4*)(p2 + 8);  xc3 = *(const float4*)(p2 + 12);
    }
    asm volatile("s_waitcnt vmcnt(0) lgkmcnt(0)" ::: "memory");
    __builtin_amdgcn_sched_barrier(0);
    __builtin_amdgcn_s_barrier();

    for (int i = 0; i < steps; ++i) {
        const int cb = i % 3, sb = (i + 2) % 3;
        const bool doStage = (i + 2) < steps;
        const bool doLoadX = (i + 3) < steps;

        if (doStage) write_A(sb, xc0, xc1, xc2, xc3);
        if (doLoadX) {
            const float* xp = xrow + kb + (i + 3) * BK3;
            xc0 = *(const float4*)(xp);      xc1 = *(const float4*)(xp + 4);
            xc2 = *(const float4*)(xp + 8);  xc3 = *(const float4*)(xp + 12);
        }
        if (doStage) stage_B(sb, kb + (i + 2) * BK3);

        // K = issues(i-1) + issues(i); issues(j) = 4*[j+2<steps] + 4*[j+3<steps]
        const int isP = (i >= 1)
            ? (((i + 1) < steps ? 4 : 0) + ((i + 2) < steps ? 4 : 0)) : 0;
        const int isC = ((i + 2) < steps ? 4 : 0) + ((i + 3) < steps ? 4 : 0);
        wait_vm(isP + isC);
        __builtin_amdgcn_sched_barrier(0);
        __builtin_amdgcn_s_barrier();           // buf cb confirmed by all waves

        compute(cb);

        __builtin_amdgcn_s_barrier();           // all done reading buf cb
    }

    // epilogue: C/D layout col=lane&15, row=(lane>>4)*4+reg
    #pragma unroll
    for (int mt = 0; mt < 4; ++mt) {
        #pragma unroll
        for (int nt = 0; nt < 4; ++nt) {
            #pragma unroll
            for (int r = 0; r < 4; ++r) {
                const int m = m0 + (wm * 4 + mt) * 16 + (lane >> 4) * 4 + r;
                const int n = (wn * 4 + nt) * 16 + (lane & 15);
                lp[(size_t)m * NEXP + n] = acc[mt][nt][r];
            }
        }
    }
}

// ---------------------------------------------------------------------------
// Kernel 2: sum K-split planes, per-token top-CAND candidates. (frozen)
// ---------------------------------------------------------------------------
__global__ __launch_bounds__(256)
void topk_cand(const float* __restrict__ logits, int* __restrict__ cand,
               int nsplit) {
    const int lane  = threadIdx.x & 63;
    const int token = blockIdx.x * 4 + (threadIdx.x >> 6);
    const float* lp = logits + (size_t)token * NEXP;

    float s[4];
    #pragma unroll
    for (int j = 0; j < 4; ++j) s[j] = 0.f;
    for (int p = 0; p < nsplit; ++p) {
        const float* pp = lp + (size_t)p * TOKENS * NEXP;
        #pragma unroll
        for (int j = 0; j < 4; ++j) s[j] += pp[j * 64 + lane];
    }

    int mye = 0;
    #pragma unroll
    for (int r = 0; r < CAND; ++r) {
        float bv = s[0];
        int   be = lane;
        #pragma unroll
        for (int j = 1; j < 4; ++j) {
            if (s[j] > bv) { bv = s[j]; be = j * 64 + lane; }
        }
        #pragma unroll
        for (int off = 32; off > 0; off >>= 1) {
            const float ov = __shfl_xor(bv, off, 64);
            const int   oe = __shfl_xor(be, off, 64);
            if (ov > bv || (ov == bv && oe < be)) { bv = ov; be = oe; }
        }
        if (lane == r) mye = be;
        if ((be & 63) == lane) s[be >> 6] = -1e30f;
    }

    if (lane < CAND) cand[token * CAND + lane] = mye;
}

// ---------------------------------------------------------------------------
// Kernel 3: fp64 rescore — round-5 structure + depth-4 W prefetch. (frozen,
// 81us, ~19 TB/s W cache-service = its structural operating point)
// ---------------------------------------------------------------------------
__global__ __launch_bounds__(256)
void rescore(const float* __restrict__ x, const float* __restrict__ w,
             const int* __restrict__ cand, float* __restrict__ out) {
    __shared__ float  xs[DIM];          // 16 KB: this token's x row
    __shared__ double stot[CAND];
    __shared__ int    sce[CAND];

    const int t = threadIdx.x, wave = t >> 6, lane = t & 63;
    const int token = blockIdx.x;

    const float* xrow = x + (size_t)token * DIM;
    #pragma unroll
    for (int r = 0; r < 4; ++r) {
        const float* gp = xrow + r * 1024 + wave * 256 + lane * 4;
        __builtin_amdgcn_global_load_lds((gas_ptr)gp,
                                         (las_ptr)&xs[r * 1024 + wave * 256],
                                         16, 0, 2 /* NT */);
    }

    int ce[3];
    const f32x4* wp[3];
    #pragma unroll
    for (int j = 0; j < 3; ++j) {
        ce[j] = __builtin_amdgcn_readfirstlane(cand[token * CAND + wave * 3 + j]);
        wp[j] = (const f32x4*)(w + (size_t)ce[j] * DIM);
    }

    double acc[3];
    #pragma unroll
    for (int j = 0; j < 3; ++j) acc[j] = 0.0;

    f32x4 wb[4][3];
    #pragma unroll
    for (int j = 0; j < 3; ++j) wb[0][j] = wp[j][lane];
    #pragma unroll
    for (int j = 0; j < 3; ++j) wb[1][j] = wp[j][64 + lane];
    #pragma unroll
    for (int j = 0; j < 3; ++j) wb[2][j] = wp[j][128 + lane];

    __syncthreads();   // xs ready

    #pragma unroll
    for (int i = 0; i < 16; ++i) {
        const int cur = i & 3, nxt = (i + 3) & 3;
        if (i < 13) {
            const int o = lane + (i + 3) * 64;
            #pragma unroll
            for (int j = 0; j < 3; ++j) wb[nxt][j] = wp[j][o];
        }
        const f32x4 xv = *(const f32x4*)&xs[(lane + i * 64) * 4];
        const double dx = (double)xv.x, dy = (double)xv.y;
        const double dz = (double)xv.z, dw = (double)xv.w;
        #pragma unroll
        for (int j = 0; j < 3; ++j) {
            const f32x4 wv = wb[cur][j];
            acc[j] = fma(dw, (double)wv.w,
                     fma(dz, (double)wv.z,
                     fma(dy, (double)wv.y,
                     fma(dx, (double)wv.x, acc[j]))));
        }
    }

    #pragma unroll
    for (int off = 32; off > 0; off >>= 1) {
        #pragma unroll
        for (int j = 0; j < 3; ++j)
            acc[j] += __shfl_xor(acc[j], off, 64);
    }

    if (lane == 0) {
        #pragma unroll
        for (int j = 0; j < 3; ++j) {
            stot[wave * 3 + j] = acc[j];
            sce[wave * 3 + j]  = ce[j];
        }
    }
    __syncthreads();

    if (wave == 0) {
        double tt[CAND];
        int    ee[CAND];
        #pragma unroll
        for (int c = 0; c < CAND; ++c) { tt[c] = stot[c]; ee[c] = sce[c]; }

        int rank[CAND];
        #pragma unroll
        for (int c = 0; c < CAND; ++c) {
            int r = 0;
            #pragma unroll
            for (int j = 0; j < CAND; ++j) {
                if (j == c) continue;
                if (tt[j] > tt[c] || (tt[j] == tt[c] && ee[j] < ee[c])) ++r;
            }
            rank[c] = r;
        }

        float sig[CAND];
        float sum = 0.f;
        #pragma unroll
        for (int c = 0; c < CAND; ++c) {
            sig[c] = 1.0f / (1.0f + expf(-(float)tt[c]));
            if (rank[c] < TOPK) sum += sig[c];
        }

        if (lane < TOPK) {
            float g = 0.f; int ei = 0;
            #pragma unroll
            for (int c = 0; c < CAND; ++c)
                if (rank[c] == lane) { g = sig[c]; ei = ee[c]; }
            out[(size_t)token * TOPK + lane] = g / sum;
            out[(size_t)TOKENS * TOPK + (size_t)token * TOPK + lane] = (float)ei;
        }
    }
}

extern "C" void kernel_launch(void* const* d_in, const int* in_sizes, int n_in,
                              void* d_out, int out_size, void* d_ws, size_t ws_size,
                              hipStream_t stream) {
    const float* x = (const float*)d_in[0];   // [8192, 4096]
    const float* w = (const float*)d_in[1];   // [256, 4096]
    float* out     = (float*)d_out;

    const size_t plane = (size_t)TOKENS * NEXP * sizeof(float);   // 8 MB
    const size_t fixed = (size_t)TOKENS * CAND * sizeof(int)
                       + (size_t)NEXP * DIM * sizeof(_Float16);
    int S = 4;
    if (ws_size < 4 * plane + fixed) S = (ws_size >= 2 * plane + fixed) ? 2 : 1;

    float*     logits = (float*)d_ws;
    int*       candp  = (int*)((char*)d_ws + (size_t)S * plane);
    _Float16*  whs    = (_Float16*)((char*)candp + (size_t)TOKENS * CAND * sizeof(int));

    convert_w<<<512, 256, 0, stream>>>(w, whs);
    dim3 ggrid(TOKENS / MT4, S);
    gemm_v4<<<ggrid, 512, 0, stream>>>(x, whs, logits, DIM / S);
    topk_cand<<<TOKENS / 4, 256, 0, stream>>>(logits, candp, S);
    rescore<<<TOKENS, 256, 0, stream>>>(x, w, candp, out);
}